// Round 7
// baseline (392.777 us; speedup 1.0000x reference)
//
#include <hip/hip_runtime.h>
#include <hip/hip_bf16.h>
#include <hip/hip_fp16.h>
#include <math.h>

#define TOKENS 32768           // 32*1024
#define EMBED  768
#define HIDDEN 3072
#define WELEMS (EMBED*HIDDEN)  // 2359296

typedef __attribute__((ext_vector_type(4))) int i32x4;          // 16 packed int8
typedef __attribute__((ext_vector_type(4))) signed char i8x4;
typedef signed char i8;

__device__ __forceinline__ float wave_reduce_sum(float v) {
    for (int o = 32; o > 0; o >>= 1) v += __shfl_down(v, o);
    return v;
}
__device__ __forceinline__ float wave_reduce_max(float v) {
    for (int o = 32; o > 0; o >>= 1) v = fmaxf(v, __shfl_down(v, o));
    return v;
}

// exact-grade GELU: erf via Abramowitz-Stegun 7.1.26 (|eps| <= 1.5e-7)
__device__ __forceinline__ float gelu_fast(float v) {
    const float z  = fabsf(v) * 0.70710678118654752440f;
    const float t  = __builtin_amdgcn_rcpf(fmaf(0.3275911f, z, 1.0f));
    float p = fmaf(1.061405429f, t, -1.453152027f);
    p = fmaf(p, t, 1.421413741f);
    p = fmaf(p, t, -0.284496736f);
    p = fmaf(p, t, 0.254829592f);
    p = p * t;
    const float e   = __expf(-z * z);
    const float erf = fmaf(-p, e, 1.0f);              // erf(|v|/sqrt2)
    const float se  = (v >= 0.f) ? erf : -erf;
    return 0.5f * v * (1.0f + se);
}

// ---- per-tensor abs-mean (two stage, deterministic) ----
__global__ __launch_bounds__(256) void k_abs_partial(const float* __restrict__ w,
                                                     float* __restrict__ out, int n) {
    float s = 0.f;
    for (int i = blockIdx.x * 256 + threadIdx.x; i < n; i += gridDim.x * 256)
        s += fabsf(w[i]);
    __shared__ float red[4];
    s = wave_reduce_sum(s);
    if ((threadIdx.x & 63) == 0) red[threadIdx.x >> 6] = s;
    __syncthreads();
    if (threadIdx.x == 0) out[blockIdx.x] = red[0] + red[1] + red[2] + red[3];
}

__global__ __launch_bounds__(256) void k_finalize(const float* __restrict__ p,
                                                  float* __restrict__ m) {
    __shared__ float r1[4], r2[4];
    float s1 = 0.f, s2 = 0.f;
    for (int i = threadIdx.x; i < 512; i += 256) { s1 += p[i]; s2 += p[512 + i]; }
    s1 = wave_reduce_sum(s1); s2 = wave_reduce_sum(s2);
    if ((threadIdx.x & 63) == 0) { r1[threadIdx.x >> 6] = s1; r2[threadIdx.x >> 6] = s2; }
    __syncthreads();
    if (threadIdx.x == 0) {
        float m1 = (r1[0] + r1[1] + r1[2] + r1[3]) / (float)WELEMS;
        float m2 = (r2[0] + r2[1] + r2[2] + r2[3]) / (float)WELEMS;
        m[0] = fmaxf(m1, 1e-5f);
        m[1] = fmaxf(m2, 1e-5f);
    }
}

// ---- ternary weight quant: wq = clip(rint(w/m), -1, 1) as int8 ----
__global__ __launch_bounds__(256) void k_quant_w(const float* __restrict__ w,
                                                 i8* __restrict__ wq,
                                                 const float* __restrict__ mp, int n) {
    const float inv = 1.0f / mp[0];
    for (int i = blockIdx.x * 256 + threadIdx.x; i < n; i += gridDim.x * 256) {
        float q = rintf(w[i] * inv);
        q = fminf(1.f, fmaxf(-1.f, q));
        wq[i] = (i8)(int)q;
    }
}

// ---- fused RMSNorm + per-token int8 absmax quant, fp32 input ----
template <int D>
__global__ __launch_bounds__(256) void k_rms_quant_f32(const float* __restrict__ x,
                                                       const float* __restrict__ g,
                                                       i8* __restrict__ xq,
                                                       float* __restrict__ sc) {
    constexpr int NV = D / 4;
    constexpr int IT = (NV + 255) / 256;
    __shared__ float reds[4], redm[4];
    const int t = blockIdx.x;
    const float4* xp = reinterpret_cast<const float4*>(x + (size_t)t * D);
    const float4* gp = reinterpret_cast<const float4*>(g);
    float4 xg[IT];
    float ssq = 0.f, amax = 0.f;
#pragma unroll
    for (int i = 0; i < IT; ++i) {
        const int idx = i * 256 + (int)threadIdx.x;
        const bool act = (NV % 256 == 0) || (idx < NV);
        if (act) {
            float4 v = xp[idx];
            float4 gv = gp[idx];
            ssq += v.x * v.x + v.y * v.y + v.z * v.z + v.w * v.w;
            xg[i].x = v.x * gv.x; xg[i].y = v.y * gv.y;
            xg[i].z = v.z * gv.z; xg[i].w = v.w * gv.w;
            amax = fmaxf(amax, fmaxf(fmaxf(fabsf(xg[i].x), fabsf(xg[i].y)),
                                     fmaxf(fabsf(xg[i].z), fabsf(xg[i].w))));
        } else {
            xg[i].x = xg[i].y = xg[i].z = xg[i].w = 0.f;
        }
    }
    ssq = wave_reduce_sum(ssq);
    amax = wave_reduce_max(amax);
    if ((threadIdx.x & 63) == 0) { reds[threadIdx.x >> 6] = ssq; redm[threadIdx.x >> 6] = amax; }
    __syncthreads();
    const float S = reds[0] + reds[1] + reds[2] + reds[3];
    const float A = fmaxf(fmaxf(redm[0], redm[1]), fmaxf(redm[2], redm[3]));
    const float rs = (float)(1.0 / sqrt((double)S / D + 1e-6));
    const float an = fmaxf(A * rs, 1e-5f);
    const float qs = rs * (127.0f / an);
    if (threadIdx.x == 0) sc[t] = an * (1.0f / 127.0f);
    i8x4* op = reinterpret_cast<i8x4*>(xq + (size_t)t * D);
#pragma unroll
    for (int i = 0; i < IT; ++i) {
        const int idx = i * 256 + (int)threadIdx.x;
        const bool act = (NV % 256 == 0) || (idx < NV);
        if (act) {
            i8x4 r;
            r[0] = (i8)(int)fminf(127.f, fmaxf(-128.f, rintf(xg[i].x * qs)));
            r[1] = (i8)(int)fminf(127.f, fmaxf(-128.f, rintf(xg[i].y * qs)));
            r[2] = (i8)(int)fminf(127.f, fmaxf(-128.f, rintf(xg[i].z * qs)));
            r[3] = (i8)(int)fminf(127.f, fmaxf(-128.f, rintf(xg[i].w * qs)));
            op[idx] = r;
        }
    }
}

// ---- fused RMSNorm + per-token int8 absmax quant, fp16 input (h) ----
template <int D>
__global__ __launch_bounds__(256) void k_rms_quant_f16(const __half* __restrict__ x,
                                                       const float* __restrict__ g,
                                                       i8* __restrict__ xq,
                                                       float* __restrict__ sc) {
    constexpr int NV = D / 8;                 // 16B = 8 halves per chunk
    constexpr int IT = (NV + 255) / 256;
    __shared__ float reds[4], redm[4];
    const int t = blockIdx.x;
    const int4* xp = reinterpret_cast<const int4*>(x + (size_t)t * D);
    const float4* gp = reinterpret_cast<const float4*>(g);
    float xg[IT][8];
    float ssq = 0.f, amax = 0.f;
#pragma unroll
    for (int i = 0; i < IT; ++i) {
        const int idx = i * 256 + (int)threadIdx.x;
        const bool act = (NV % 256 == 0) || (idx < NV);
        if (act) {
            int4 raw = xp[idx];
            const __half2* hp = reinterpret_cast<const __half2*>(&raw);
            float4 g0 = gp[idx * 2];
            float4 g1 = gp[idx * 2 + 1];
            float gv[8] = {g0.x, g0.y, g0.z, g0.w, g1.x, g1.y, g1.z, g1.w};
#pragma unroll
            for (int j = 0; j < 4; ++j) {
                float2 f = __half22float2(hp[j]);
                float a0 = f.x, a1 = f.y;
                ssq += a0 * a0 + a1 * a1;
                xg[i][j * 2]     = a0 * gv[j * 2];
                xg[i][j * 2 + 1] = a1 * gv[j * 2 + 1];
                amax = fmaxf(amax, fmaxf(fabsf(xg[i][j * 2]), fabsf(xg[i][j * 2 + 1])));
            }
        } else {
#pragma unroll
            for (int j = 0; j < 8; ++j) xg[i][j] = 0.f;
        }
    }
    ssq = wave_reduce_sum(ssq);
    amax = wave_reduce_max(amax);
    if ((threadIdx.x & 63) == 0) { reds[threadIdx.x >> 6] = ssq; redm[threadIdx.x >> 6] = amax; }
    __syncthreads();
    const float S = reds[0] + reds[1] + reds[2] + reds[3];
    const float A = fmaxf(fmaxf(redm[0], redm[1]), fmaxf(redm[2], redm[3]));
    const float rs = (float)(1.0 / sqrt((double)S / D + 1e-6));
    const float an = fmaxf(A * rs, 1e-5f);
    const float qs = rs * (127.0f / an);
    if (threadIdx.x == 0) sc[t] = an * (1.0f / 127.0f);
    i8x4* op = reinterpret_cast<i8x4*>(xq + (size_t)t * D);
#pragma unroll
    for (int i = 0; i < IT; ++i) {
        const int idx = i * 256 + (int)threadIdx.x;
        const bool act = (NV % 256 == 0) || (idx < NV);
        if (act) {
            i8x4 r0, r1;
#pragma unroll
            for (int j = 0; j < 4; ++j)
                r0[j] = (i8)(int)fminf(127.f, fmaxf(-128.f, rintf(xg[i][j] * qs)));
#pragma unroll
            for (int j = 0; j < 4; ++j)
                r1[j] = (i8)(int)fminf(127.f, fmaxf(-128.f, rintf(xg[i][4 + j] * qs)));
            op[idx * 2]     = r0;
            op[idx * 2 + 1] = r1;
        }
    }
}

// ---- 128x128 int8 MFMA GEMM, BK=128, counted-vmcnt double-buffer pipeline ----
// Per K-tile: STAGE(next -> buf^1)  [8 x global_load_lds, stay in flight]
//             s_waitcnt vmcnt(8)    [waits only PREVIOUS tile's loads ~0 stall]
//             s_barrier             [raw: no compiler vmcnt(0) drain]
//             ds_read + MFMA (setprio around MFMA clusters)
//             s_barrier             [all reads consumed -> buffer reusable]
// Correctness: barrier after per-thread vmcnt(8) => all tile-t LDS data landed;
// trailing barrier => no wave re-stages buf[t&1] until all waves' ds_reads of it
// were consumed by issued MFMAs (lgkmcnt enforced by compiler before MFMA).
// T2 XOR swizzle kept (conflicts=0, rule-21 both-sides); XCD swizzle on grid.
template <bool GELU, typename OutT>
__global__ __launch_bounds__(256, 2) void k_gemm_i8(const i8* __restrict__ A,
                                                    const i8* __restrict__ B,
                                                    OutT* __restrict__ C,
                                                    const float* __restrict__ rsc,
                                                    const float* __restrict__ msc,
                                                    int nbx, int N, int K) {
    __shared__ i8 As[2][128 * 128];
    __shared__ i8 Bs[2][128 * 128];

    // bijective XCD swizzle (m204)
    const int nwg = (int)gridDim.x;
    const int id  = (int)blockIdx.x;
    const int q = nwg >> 3, r = nwg & 7;
    const int xcd = id & 7, sub = id >> 3;
    const int swz = (xcd < r ? xcd * (q + 1) : r * (q + 1) + (xcd - r) * q) + sub;
    const int bx = swz % nbx;
    const int by = swz / nbx;

    const int tid  = threadIdx.x;
    const int lane = tid & 63;
    const int wave = tid >> 6;
    const int wr = wave >> 1, wc = wave & 1;          // 2x2 wave grid, 64x64 each
    const size_t rowBase = (size_t)by * 128;
    const size_t colBase = (size_t)bx * 128;
    const float ms = msc[0];

    i32x4 acc[4][4] = {};

    // staging: thread t -> row srow=t/8 (0..31), chunk cc=t%8 (linear LDS dest);
    // global source chunk = cc ^ (srow&7)  [inverse swizzle, rule 21]
    const int srow = tid >> 3;
    const int cc   = tid & 7;
    const int gcol = (cc ^ (srow & 7)) * 16;
    const i8* gA0 = A + (rowBase + srow) * (size_t)K + gcol;
    const i8* gB0 = B + (colBase + srow) * (size_t)K + gcol;
    const int lOff = srow * 128 + cc * 16;

    const int frow = lane & 15;
    const int fko  = (lane >> 4) * 16;
    const int rswz = (frow & 7) << 4;                // read-side XOR swizzle

    const int nt = K >> 7;                           // BK=128 tiles

#define STAGE(kk, buf)                                                                   \
    {                                                                                    \
        const int _k0 = (kk) << 7;                                                       \
        _Pragma("unroll")                                                                \
        for (int _r = 0; _r < 4; ++_r) {                                                 \
            __builtin_amdgcn_global_load_lds(                                            \
                (const __attribute__((address_space(1))) void*)(gA0 + (size_t)_r * 32 * K + _k0), \
                (__attribute__((address_space(3))) void*)(&As[buf][lOff + _r * 32 * 128]), 16, 0, 0); \
            __builtin_amdgcn_global_load_lds(                                            \
                (const __attribute__((address_space(1))) void*)(gB0 + (size_t)_r * 32 * K + _k0), \
                (__attribute__((address_space(3))) void*)(&Bs[buf][lOff + _r * 32 * 128]), 16, 0, 0); \
        }                                                                                \
    }

    STAGE(0, 0);                                     // prologue: tile 0 -> buf 0

    for (int t = 0; t < nt; ++t) {
        const int cur = t & 1;
        if (t + 1 < nt) {
            STAGE(t + 1, cur ^ 1);                   // next tile's 8 loads in flight
            asm volatile("s_waitcnt vmcnt(8)" ::: "memory");   // tile t's loads done
        } else {
            asm volatile("s_waitcnt vmcnt(0)" ::: "memory");
        }
        __builtin_amdgcn_s_barrier();                // raw: no vmcnt(0) drain
        __builtin_amdgcn_sched_barrier(0);           // no ds_read hoists above
#pragma unroll
        for (int ks = 0; ks < 2; ++ks) {
            i32x4 af[4], bv[4];
#pragma unroll
            for (int mi = 0; mi < 4; ++mi)
                af[mi] = *(const i32x4*)(&As[cur][(wr * 64 + mi * 16 + frow) * 128
                                                  + ((ks * 64 + fko) ^ rswz)]);
#pragma unroll
            for (int ni = 0; ni < 4; ++ni)
                bv[ni] = *(const i32x4*)(&Bs[cur][(wc * 64 + ni * 16 + frow) * 128
                                                  + ((ks * 64 + fko) ^ rswz)]);
            __builtin_amdgcn_s_setprio(1);
#pragma unroll
            for (int mi = 0; mi < 4; ++mi)
#pragma unroll
                for (int ni = 0; ni < 4; ++ni)
                    acc[mi][ni] = __builtin_amdgcn_mfma_i32_16x16x64_i8(
                        af[mi], bv[ni], acc[mi][ni], 0, 0, 0);
            __builtin_amdgcn_s_setprio(0);
        }
        __builtin_amdgcn_sched_barrier(0);           // no MFMA/ds_read sinks below
        __builtin_amdgcn_s_barrier();                // buf[cur] free for re-stage
        __builtin_amdgcn_sched_barrier(0);
    }
#undef STAGE

    // C/D layout: col = lane&15, row = (lane>>4)*4 + reg
    const int ccol = lane & 15;
    const int crg  = lane >> 4;
#pragma unroll
    for (int mi = 0; mi < 4; ++mi) {
#pragma unroll
        for (int i = 0; i < 4; ++i) {
            size_t row = rowBase + wr * 64 + mi * 16 + crg * 4 + i;
            float rscale = rsc[row] * ms;
#pragma unroll
            for (int ni = 0; ni < 4; ++ni) {
                size_t col = colBase + wc * 64 + ni * 16 + ccol;
                float v = (float)acc[mi][ni][i] * rscale;
                if (GELU) v = gelu_fast(v);
                C[row * (size_t)N + col] = (OutT)v;
            }
        }
    }
}

extern "C" void kernel_launch(void* const* d_in, const int* in_sizes, int n_in,
                              void* d_out, int out_size, void* d_ws, size_t ws_size,
                              hipStream_t stream) {
    const float* x  = (const float*)d_in[0];
    const float* w1 = (const float*)d_in[1];
    const float* g1 = (const float*)d_in[2];
    const float* w2 = (const float*)d_in[3];
    const float* g2 = (const float*)d_in[4];
    float* out = (float*)d_out;

    // ---- fixed workspace region ----
    char* ws = (char*)d_ws;
    float* partials = (float*)ws;                        //       0: 4096 B
    float* mvals    = (float*)(ws + 4096);               //    4096: 256 B
    float* a        = (float*)(ws + 4352);               //    4352: 131072 B
    float* b        = (float*)(ws + 135424);             //  135424: 131072 B
    i8*    wq1      = (i8*)(ws + 266496);                //  266496: 2359296 B
    i8*    wq2      = (i8*)(ws + 2625792);               // 2625792: 2359296 B
    const size_t FIXED = 4985088;
    char* chunkMem = ws + FIXED;

    // ---- chunking: adaptive to ws_size (ws >= 332MB -> single chunk) ----
    const size_t PER_TOK = 768 + 6144 + 3072;            // xq + h(fp16) + hq = 9984 B
    size_t avail = (ws_size > FIXED) ? (ws_size - FIXED) : 0;
    long long ch = (long long)(avail / PER_TOK);
    ch &= ~255LL;
    if (ch < 256) ch = 256;
    if (ch > TOKENS) ch = TOKENS;
    const int CH = (int)ch;

    // ---- weight prep ----
    k_abs_partial<<<512, 256, 0, stream>>>(w1, partials, WELEMS);
    k_abs_partial<<<512, 256, 0, stream>>>(w2, partials + 512, WELEMS);
    k_finalize<<<1, 256, 0, stream>>>(partials, mvals);
    k_quant_w<<<2048, 256, 0, stream>>>(w1, wq1, mvals + 0, WELEMS);
    k_quant_w<<<2048, 256, 0, stream>>>(w2, wq2, mvals + 1, WELEMS);

    // ---- token chunks: rms1 -> gemm1(+gelu, fp16 h) -> rms2 -> gemm2 ----
    for (int base = 0; base < TOKENS; base += CH) {
        const int rows = (TOKENS - base < CH) ? (TOKENS - base) : CH;   // multiple of 256
        i8*     xqc = (i8*)chunkMem;
        __half* hc  = (__half*)(chunkMem + (size_t)CH * 768);
        i8*     hqc = (i8*)(chunkMem + (size_t)CH * 768 + (size_t)CH * 6144);

        const int nby = rows / 128;
        const int nbx1 = HIDDEN / 128;    // 24
        const int nbx2 = EMBED / 128;     // 6

        k_rms_quant_f32<EMBED><<<rows, 256, 0, stream>>>(
            x + (size_t)base * EMBED, g1, xqc, a + base);
        k_gemm_i8<true, __half><<<nbx1 * nby, 256, 0, stream>>>(
            xqc, wq1, hc, a + base, mvals + 0, nbx1, HIDDEN, EMBED);
        k_rms_quant_f16<HIDDEN><<<rows, 256, 0, stream>>>(
            hc, g2, hqc, b + base);
        k_gemm_i8<false, float><<<nbx2 * nby, 256, 0, stream>>>(
            hqc, wq2, out + (size_t)base * EMBED, b + base, mvals + 1, nbx2, EMBED, HIDDEN);
    }
}

// Round 8
// 387.088 us; speedup vs baseline: 1.0147x; 1.0147x over previous
//
#include <hip/hip_runtime.h>
#include <hip/hip_bf16.h>
#include <hip/hip_fp16.h>
#include <math.h>

#define TOKENS 32768           // 32*1024
#define EMBED  768
#define HIDDEN 3072
#define WELEMS (EMBED*HIDDEN)  // 2359296

typedef __attribute__((ext_vector_type(4))) int i32x4;          // 16 packed int8
typedef __attribute__((ext_vector_type(4))) signed char i8x4;
typedef signed char i8;

__device__ __forceinline__ float wave_reduce_sum(float v) {
    for (int o = 32; o > 0; o >>= 1) v += __shfl_down(v, o);
    return v;
}
__device__ __forceinline__ float wave_reduce_max(float v) {
    for (int o = 32; o > 0; o >>= 1) v = fmaxf(v, __shfl_down(v, o));
    return v;
}

// exact-grade GELU: erf via Abramowitz-Stegun 7.1.26 (|eps| <= 1.5e-7)
__device__ __forceinline__ float gelu_fast(float v) {
    const float z  = fabsf(v) * 0.70710678118654752440f;
    const float t  = __builtin_amdgcn_rcpf(fmaf(0.3275911f, z, 1.0f));
    float p = fmaf(1.061405429f, t, -1.453152027f);
    p = fmaf(p, t, 1.421413741f);
    p = fmaf(p, t, -0.284496736f);
    p = fmaf(p, t, 0.254829592f);
    p = p * t;
    const float e   = __expf(-z * z);
    const float erf = fmaf(-p, e, 1.0f);              // erf(|v|/sqrt2)
    const float se  = (v >= 0.f) ? erf : -erf;
    return 0.5f * v * (1.0f + se);
}

// ---- per-tensor abs-mean (two stage, deterministic) ----
__global__ __launch_bounds__(256) void k_abs_partial(const float* __restrict__ w,
                                                     float* __restrict__ out, int n) {
    float s = 0.f;
    for (int i = blockIdx.x * 256 + threadIdx.x; i < n; i += gridDim.x * 256)
        s += fabsf(w[i]);
    __shared__ float red[4];
    s = wave_reduce_sum(s);
    if ((threadIdx.x & 63) == 0) red[threadIdx.x >> 6] = s;
    __syncthreads();
    if (threadIdx.x == 0) out[blockIdx.x] = red[0] + red[1] + red[2] + red[3];
}

__global__ __launch_bounds__(256) void k_finalize(const float* __restrict__ p,
                                                  float* __restrict__ m) {
    __shared__ float r1[4], r2[4];
    float s1 = 0.f, s2 = 0.f;
    for (int i = threadIdx.x; i < 512; i += 256) { s1 += p[i]; s2 += p[512 + i]; }
    s1 = wave_reduce_sum(s1); s2 = wave_reduce_sum(s2);
    if ((threadIdx.x & 63) == 0) { r1[threadIdx.x >> 6] = s1; r2[threadIdx.x >> 6] = s2; }
    __syncthreads();
    if (threadIdx.x == 0) {
        float m1 = (r1[0] + r1[1] + r1[2] + r1[3]) / (float)WELEMS;
        float m2 = (r2[0] + r2[1] + r2[2] + r2[3]) / (float)WELEMS;
        m[0] = fmaxf(m1, 1e-5f);
        m[1] = fmaxf(m2, 1e-5f);
    }
}

// ---- ternary weight quant: wq = clip(rint(w/m), -1, 1) as int8 ----
__global__ __launch_bounds__(256) void k_quant_w(const float* __restrict__ w,
                                                 i8* __restrict__ wq,
                                                 const float* __restrict__ mp, int n) {
    const float inv = 1.0f / mp[0];
    for (int i = blockIdx.x * 256 + threadIdx.x; i < n; i += gridDim.x * 256) {
        float q = rintf(w[i] * inv);
        q = fminf(1.f, fmaxf(-1.f, q));
        wq[i] = (i8)(int)q;
    }
}

// ---- fused RMSNorm + per-token int8 absmax quant, fp32 input ----
template <int D>
__global__ __launch_bounds__(256) void k_rms_quant_f32(const float* __restrict__ x,
                                                       const float* __restrict__ g,
                                                       i8* __restrict__ xq,
                                                       float* __restrict__ sc) {
    constexpr int NV = D / 4;
    constexpr int IT = (NV + 255) / 256;
    __shared__ float reds[4], redm[4];
    const int t = blockIdx.x;
    const float4* xp = reinterpret_cast<const float4*>(x + (size_t)t * D);
    const float4* gp = reinterpret_cast<const float4*>(g);
    float4 xg[IT];
    float ssq = 0.f, amax = 0.f;
#pragma unroll
    for (int i = 0; i < IT; ++i) {
        const int idx = i * 256 + (int)threadIdx.x;
        const bool act = (NV % 256 == 0) || (idx < NV);
        if (act) {
            float4 v = xp[idx];
            float4 gv = gp[idx];
            ssq += v.x * v.x + v.y * v.y + v.z * v.z + v.w * v.w;
            xg[i].x = v.x * gv.x; xg[i].y = v.y * gv.y;
            xg[i].z = v.z * gv.z; xg[i].w = v.w * gv.w;
            amax = fmaxf(amax, fmaxf(fmaxf(fabsf(xg[i].x), fabsf(xg[i].y)),
                                     fmaxf(fabsf(xg[i].z), fabsf(xg[i].w))));
        } else {
            xg[i].x = xg[i].y = xg[i].z = xg[i].w = 0.f;
        }
    }
    ssq = wave_reduce_sum(ssq);
    amax = wave_reduce_max(amax);
    if ((threadIdx.x & 63) == 0) { reds[threadIdx.x >> 6] = ssq; redm[threadIdx.x >> 6] = amax; }
    __syncthreads();
    const float S = reds[0] + reds[1] + reds[2] + reds[3];
    const float A = fmaxf(fmaxf(redm[0], redm[1]), fmaxf(redm[2], redm[3]));
    const float rs = (float)(1.0 / sqrt((double)S / D + 1e-6));
    const float an = fmaxf(A * rs, 1e-5f);
    const float qs = rs * (127.0f / an);
    if (threadIdx.x == 0) sc[t] = an * (1.0f / 127.0f);
    i8x4* op = reinterpret_cast<i8x4*>(xq + (size_t)t * D);
#pragma unroll
    for (int i = 0; i < IT; ++i) {
        const int idx = i * 256 + (int)threadIdx.x;
        const bool act = (NV % 256 == 0) || (idx < NV);
        if (act) {
            i8x4 r;
            r[0] = (i8)(int)fminf(127.f, fmaxf(-128.f, rintf(xg[i].x * qs)));
            r[1] = (i8)(int)fminf(127.f, fmaxf(-128.f, rintf(xg[i].y * qs)));
            r[2] = (i8)(int)fminf(127.f, fmaxf(-128.f, rintf(xg[i].z * qs)));
            r[3] = (i8)(int)fminf(127.f, fmaxf(-128.f, rintf(xg[i].w * qs)));
            op[idx] = r;
        }
    }
}

// ---- fused RMSNorm + per-token int8 absmax quant, fp16 input (h) ----
template <int D>
__global__ __launch_bounds__(256) void k_rms_quant_f16(const __half* __restrict__ x,
                                                       const float* __restrict__ g,
                                                       i8* __restrict__ xq,
                                                       float* __restrict__ sc) {
    constexpr int NV = D / 8;                 // 16B = 8 halves per chunk
    constexpr int IT = (NV + 255) / 256;
    __shared__ float reds[4], redm[4];
    const int t = blockIdx.x;
    const int4* xp = reinterpret_cast<const int4*>(x + (size_t)t * D);
    const float4* gp = reinterpret_cast<const float4*>(g);
    float xg[IT][8];
    float ssq = 0.f, amax = 0.f;
#pragma unroll
    for (int i = 0; i < IT; ++i) {
        const int idx = i * 256 + (int)threadIdx.x;
        const bool act = (NV % 256 == 0) || (idx < NV);
        if (act) {
            int4 raw = xp[idx];
            const __half2* hp = reinterpret_cast<const __half2*>(&raw);
            float4 g0 = gp[idx * 2];
            float4 g1 = gp[idx * 2 + 1];
            float gv[8] = {g0.x, g0.y, g0.z, g0.w, g1.x, g1.y, g1.z, g1.w};
#pragma unroll
            for (int j = 0; j < 4; ++j) {
                float2 f = __half22float2(hp[j]);
                float a0 = f.x, a1 = f.y;
                ssq += a0 * a0 + a1 * a1;
                xg[i][j * 2]     = a0 * gv[j * 2];
                xg[i][j * 2 + 1] = a1 * gv[j * 2 + 1];
                amax = fmaxf(amax, fmaxf(fabsf(xg[i][j * 2]), fabsf(xg[i][j * 2 + 1])));
            }
        } else {
#pragma unroll
            for (int j = 0; j < 8; ++j) xg[i][j] = 0.f;
        }
    }
    ssq = wave_reduce_sum(ssq);
    amax = wave_reduce_max(amax);
    if ((threadIdx.x & 63) == 0) { reds[threadIdx.x >> 6] = ssq; redm[threadIdx.x >> 6] = amax; }
    __syncthreads();
    const float S = reds[0] + reds[1] + reds[2] + reds[3];
    const float A = fmaxf(fmaxf(redm[0], redm[1]), fmaxf(redm[2], redm[3]));
    const float rs = (float)(1.0 / sqrt((double)S / D + 1e-6));
    const float an = fmaxf(A * rs, 1e-5f);
    const float qs = rs * (127.0f / an);
    if (threadIdx.x == 0) sc[t] = an * (1.0f / 127.0f);
    i8x4* op = reinterpret_cast<i8x4*>(xq + (size_t)t * D);
#pragma unroll
    for (int i = 0; i < IT; ++i) {
        const int idx = i * 256 + (int)threadIdx.x;
        const bool act = (NV % 256 == 0) || (idx < NV);
        if (act) {
            i8x4 r0, r1;
#pragma unroll
            for (int j = 0; j < 4; ++j)
                r0[j] = (i8)(int)fminf(127.f, fmaxf(-128.f, rintf(xg[i][j] * qs)));
#pragma unroll
            for (int j = 0; j < 4; ++j)
                r1[j] = (i8)(int)fminf(127.f, fmaxf(-128.f, rintf(xg[i][4 + j] * qs)));
            op[idx * 2]     = r0;
            op[idx * 2 + 1] = r1;
        }
    }
}

// ==== 8-phase 256x256 int8 MFMA GEMM (m201 template, i8 port) ====
// BM=BN=256, K-step 128B; 512 thr = 8 waves (2M x 4N); per-wave 128x64 out.
// LDS 128KB: As[2]/Bs[2] of [256][128] (tile parity buffers). Per K-tile 4
// phases: {ds_read subtile || stage 1 half-tile -> barrier -> 16 MFMA
// (setprio 1) -> barrier}. Counted waits ONLY at phase ends 4/8 (vmcnt(4):
// youngest-needed half is always followed by exactly 2 halves = 4 loads;
// vmcnt(0) on last iter where nothing younger is in flight). Staging targets
// only barrier-confirmed-freed LDS: B of a tile is read only in its first
// consume-phase (freed after), A halves freed after consume-phase 4.
// T2 XOR swizzle kept (conflicts=0, rule-21 both-sides); XCD swizzle (m204).
template <bool GELU, typename OutT>
__global__ __launch_bounds__(512, 2) void k_gemm8(const i8* __restrict__ A,
                                                  const i8* __restrict__ B,
                                                  OutT* __restrict__ C,
                                                  const float* __restrict__ rsc,
                                                  const float* __restrict__ msc,
                                                  int nbx, int N, int K) {
    __shared__ i8 As[2][256 * 128];
    __shared__ i8 Bs[2][256 * 128];

    // bijective XCD swizzle
    const int nwg = (int)gridDim.x;
    const int id  = (int)blockIdx.x;
    const int q8 = nwg >> 3, r8 = nwg & 7;
    const int xcd = id & 7, sub = id >> 3;
    const int swz = (xcd < r8 ? xcd * (q8 + 1) : r8 * (q8 + 1) + (xcd - r8) * q8) + sub;
    const int bx = swz % nbx;
    const int by = swz / nbx;

    const int tid  = (int)threadIdx.x;
    const int lane = tid & 63;
    const int wave = tid >> 6;
    const int wr = wave >> 2;            // 0..1 (M)
    const int wc = wave & 3;             // 0..3 (N)
    const size_t rowBase = (size_t)by * 256;
    const size_t colBase = (size_t)bx * 256;
    const float ms = msc[0];

    i32x4 acc[8][4] = {};

    // staging map: thread t -> row srow=t>>3 (0..63), chunk cc=t&7 (linear LDS
    // dest = base + tid*16, lane-linear per wave); global chunk inverse-swizzled.
    const int srow = tid >> 3;
    const int cc   = tid & 7;
    const int gch  = (cc ^ (srow & 7)) * 16;
    const i8* gA0 = A + (rowBase + srow) * (size_t)K + gch;
    const i8* gB0 = B + (colBase + srow) * (size_t)K + gch;

    const int frow = lane & 15;
    const int fko  = (lane >> 4) * 16;
    const int rswz = (frow & 7) << 4;    // read-side XOR swizzle

    const int nt = K >> 7;               // 128B K-tiles (even: K%256==0)
    const int niters = nt >> 1;

    // stage one half-tile (128 rows) of tensor TS from GP, K-tile kk -> buf
#define STG(TS, GP, buf, h, kk)                                                \
    { _Pragma("unroll")                                                        \
      for (int _r = 0; _r < 2; ++_r)                                           \
          __builtin_amdgcn_global_load_lds(                                    \
              (const __attribute__((address_space(1))) void*)                  \
                  (GP + (size_t)((h) * 128 + _r * 64) * K + ((size_t)(kk) << 7)), \
              (__attribute__((address_space(3))) void*)                        \
                  (&TS[buf][((h) * 128 + _r * 64) * 128 + tid * 16]),          \
              16, 0, 0); }

    // prologue: tile0 B,A -> buf0; tile1 B -> buf1  (tile1 A staged at ph0/ph1)
    STG(Bs, gB0, 0, 0, 0) STG(Bs, gB0, 0, 1, 0)
    STG(As, gA0, 0, 0, 0) STG(As, gA0, 0, 1, 0)
    STG(Bs, gB0, 1, 0, 1) STG(Bs, gB0, 1, 1, 1)
    asm volatile("s_waitcnt vmcnt(4)" ::: "memory");   // tile0 complete
    __builtin_amdgcn_s_barrier();
    __builtin_amdgcn_sched_barrier(0);

    i32x4 bv[8];                         // [ni*2+ks], persists across 4 phases

#define LOADBV(cb)                                                             \
    _Pragma("unroll")                                                          \
    for (int ni = 0; ni < 4; ++ni)                                             \
        _Pragma("unroll")                                                      \
        for (int ks = 0; ks < 2; ++ks)                                         \
            bv[ni * 2 + ks] = *(const i32x4*)(&Bs[cb][(wc * 64 + ni * 16 + frow) * 128 \
                                                      + ((ks * 64 + fko) ^ rswz)]);

#define PHASE(cb, q, STAGE_CODE, TAIL_CODE)                                    \
    {                                                                          \
        i32x4 a0[2], a1[2];                                                    \
        _Pragma("unroll")                                                      \
        for (int ks = 0; ks < 2; ++ks) {                                       \
            a0[ks] = *(const i32x4*)(&As[cb][(wr * 128 + (2 * (q)) * 16 + frow) * 128 \
                                             + ((ks * 64 + fko) ^ rswz)]);     \
            a1[ks] = *(const i32x4*)(&As[cb][(wr * 128 + (2 * (q) + 1) * 16 + frow) * 128 \
                                             + ((ks * 64 + fko) ^ rswz)]);     \
        }                                                                      \
        STAGE_CODE                                                             \
        __builtin_amdgcn_s_barrier();                                          \
        __builtin_amdgcn_sched_barrier(0);                                     \
        __builtin_amdgcn_s_setprio(1);                                         \
        _Pragma("unroll")                                                      \
        for (int ks = 0; ks < 2; ++ks)                                         \
            _Pragma("unroll")                                                  \
            for (int ni = 0; ni < 4; ++ni) {                                   \
                acc[2 * (q)][ni] = __builtin_amdgcn_mfma_i32_16x16x64_i8(      \
                    a0[ks], bv[ni * 2 + ks], acc[2 * (q)][ni], 0, 0, 0);       \
                acc[2 * (q) + 1][ni] = __builtin_amdgcn_mfma_i32_16x16x64_i8(  \
                    a1[ks], bv[ni * 2 + ks], acc[2 * (q) + 1][ni], 0, 0, 0);   \
            }                                                                  \
        __builtin_amdgcn_s_setprio(0);                                         \
        __builtin_amdgcn_sched_barrier(0);                                     \
        TAIL_CODE                                                              \
        __builtin_amdgcn_s_barrier();                                          \
        __builtin_amdgcn_sched_barrier(0);                                     \
    }

    for (int it = 0; it < niters; ++it) {
        const int tO  = 2 * it + 1;
        const int tE2 = 2 * it + 2;
        const int tO2 = 2 * it + 3;
        const bool hE2 = (tE2 < nt);     // false only on last iter
        const bool hO2 = (tO2 < nt);

        // ---- phases 1-4: consume buf0 (tile 2it) ----
        LOADBV(0)
        PHASE(0, 0, { STG(As, gA0, 1, 0, tO) }, {})
        PHASE(0, 1, { STG(As, gA0, 1, 1, tO)
                      if (hE2) STG(Bs, gB0, 0, 0, tE2) }, {})
        PHASE(0, 2, { if (hE2) STG(Bs, gB0, 0, 1, tE2) }, {})
        PHASE(0, 3, {},
              { if (hE2) { asm volatile("s_waitcnt vmcnt(4)" ::: "memory"); }
                else     { asm volatile("s_waitcnt vmcnt(0)" ::: "memory"); } })
        // ---- phases 5-8: consume buf1 (tile 2it+1) ----
        LOADBV(1)
        PHASE(1, 0, { if (hE2) STG(As, gA0, 0, 0, tE2) }, {})
        PHASE(1, 1, { if (hE2) STG(As, gA0, 0, 1, tE2)
                      if (hO2) STG(Bs, gB0, 1, 0, tO2) }, {})
        PHASE(1, 2, { if (hO2) STG(Bs, gB0, 1, 1, tO2) }, {})
        PHASE(1, 3, {},
              { if (hE2) { asm volatile("s_waitcnt vmcnt(4)" ::: "memory"); } })
    }
#undef PHASE
#undef LOADBV
#undef STG

    // C/D layout: col = lane&15, row = (lane>>4)*4 + reg
    const int ccol = lane & 15;
    const int crg  = lane >> 4;
#pragma unroll
    for (int mi = 0; mi < 8; ++mi) {
#pragma unroll
        for (int i = 0; i < 4; ++i) {
            size_t row = rowBase + wr * 128 + mi * 16 + crg * 4 + i;
            float rscale = rsc[row] * ms;
#pragma unroll
            for (int ni = 0; ni < 4; ++ni) {
                size_t col = colBase + wc * 64 + ni * 16 + ccol;
                float v = (float)acc[mi][ni][i] * rscale;
                if (GELU) v = gelu_fast(v);
                C[row * (size_t)N + col] = (OutT)v;
            }
        }
    }
}

extern "C" void kernel_launch(void* const* d_in, const int* in_sizes, int n_in,
                              void* d_out, int out_size, void* d_ws, size_t ws_size,
                              hipStream_t stream) {
    const float* x  = (const float*)d_in[0];
    const float* w1 = (const float*)d_in[1];
    const float* g1 = (const float*)d_in[2];
    const float* w2 = (const float*)d_in[3];
    const float* g2 = (const float*)d_in[4];
    float* out = (float*)d_out;

    // ---- fixed workspace region ----
    char* ws = (char*)d_ws;
    float* partials = (float*)ws;                        //       0: 4096 B
    float* mvals    = (float*)(ws + 4096);               //    4096: 256 B
    float* a        = (float*)(ws + 4352);               //    4352: 131072 B
    float* b        = (float*)(ws + 135424);             //  135424: 131072 B
    i8*    wq1      = (i8*)(ws + 266496);                //  266496: 2359296 B
    i8*    wq2      = (i8*)(ws + 2625792);               // 2625792: 2359296 B
    const size_t FIXED = 4985088;
    char* chunkMem = ws + FIXED;

    // ---- chunking: adaptive to ws_size (ws >= ~332MB -> single chunk) ----
    const size_t PER_TOK = 768 + 6144 + 3072;            // xq + h(fp16) + hq = 9984 B
    size_t avail = (ws_size > FIXED) ? (ws_size - FIXED) : 0;
    long long ch = (long long)(avail / PER_TOK);
    ch &= ~255LL;                                        // multiple of 256 (BM tiles)
    if (ch < 256) ch = 256;
    if (ch > TOKENS) ch = TOKENS;
    const int CH = (int)ch;

    // ---- weight prep ----
    k_abs_partial<<<512, 256, 0, stream>>>(w1, partials, WELEMS);
    k_abs_partial<<<512, 256, 0, stream>>>(w2, partials + 512, WELEMS);
    k_finalize<<<1, 256, 0, stream>>>(partials, mvals);
    k_quant_w<<<2048, 256, 0, stream>>>(w1, wq1, mvals + 0, WELEMS);
    k_quant_w<<<2048, 256, 0, stream>>>(w2, wq2, mvals + 1, WELEMS);

    // ---- token chunks: rms1 -> gemm1(+gelu, fp16 h) -> rms2 -> gemm2 ----
    for (int base = 0; base < TOKENS; base += CH) {
        const int rows = (TOKENS - base < CH) ? (TOKENS - base) : CH;   // mult of 256
        i8*     xqc = (i8*)chunkMem;
        __half* hc  = (__half*)(chunkMem + (size_t)CH * 768);
        i8*     hqc = (i8*)(chunkMem + (size_t)CH * 768 + (size_t)CH * 6144);

        const int nby  = rows / 256;
        const int nbx1 = HIDDEN / 256;    // 12
        const int nbx2 = EMBED / 256;     // 3

        k_rms_quant_f32<EMBED><<<rows, 256, 0, stream>>>(
            x + (size_t)base * EMBED, g1, xqc, a + base);
        k_gemm8<true, __half><<<nbx1 * nby, 512, 0, stream>>>(
            xqc, wq1, hc, a + base, mvals + 0, nbx1, HIDDEN, EMBED);
        k_rms_quant_f16<HIDDEN><<<rows, 256, 0, stream>>>(
            hc, g2, hqc, b + base);
        k_gemm8<false, float><<<nbx2 * nby, 512, 0, stream>>>(
            hqc, wq2, out + (size_t)base * EMBED, b + base, mvals + 1, nbx2, EMBED, HIDDEN);
    }
}